// Round 4
// baseline (5510.066 us; speedup 1.0000x reference)
//
#include <hip/hip_runtime.h>

#define HDIM 512
#define G4H 2048
#define SEQLEN 512
#define BATCH 128
#define NG 8          // groups
#define GB 16         // batch rows per group
#define WSCALE 64.0f
#define WINV   0.015625f

typedef __attribute__((ext_vector_type(8))) _Float16 f16x8;
typedef __attribute__((ext_vector_type(4))) float f32x4;

__device__ __forceinline__ unsigned short f2h(float x){
  return __builtin_bit_cast(unsigned short, (_Float16)x);
}
__device__ __forceinline__ void split_f16(float v, unsigned short& h, unsigned short& l){
  _Float16 a = (_Float16)v;
  _Float16 b = (_Float16)(v - (float)a);
  h = __builtin_bit_cast(unsigned short, a);
  l = __builtin_bit_cast(unsigned short, b);
}

// workspace layout
#define WS_CNT   0                                   // 8 counters, 256B apart
#define WS_HBUFH 4096                                // [8][2][16][512] f16 = 256KB
#define WS_HBUFL (4096 + 262144)                     // lo plane, 256KB
#define WS_HFIN  (4096 + 2*262144)                   // [128][512] f32 = 256KB

__global__ __launch_bounds__(256, 1)
void lstm_fused(const int* __restrict__ input, const float* __restrict__ emb,
                const float* __restrict__ W_ih, const float* __restrict__ W_hh,
                const float* __restrict__ b_lstm, char* __restrict__ ws)
{
  __shared__ __align__(16) unsigned short Ax [16*512];  // x hi-plane, 16KB
  __shared__ __align__(16) unsigned short AhH[16*512];  // h hi-plane, 16KB
  __shared__ __align__(16) unsigned short AhL[16*512];  // h lo-plane, 16KB
  __shared__ float gbuf[4][16][16];                     // gate exchange, 4KB
  __shared__ int idxs[SEQLEN*GB];                       // 32KB  -> 84KB total, 1 block/CU
  __shared__ int bail;

  const int tid  = threadIdx.x;
  const int lane = tid & 63;
  const int wv   = tid >> 6;          // wave index == gate index (i,f,g,o)
  const int bid  = blockIdx.x;
  const int g    = bid & 7;           // group
  const int m    = bid >> 3;          // member 0..31: owns h-cols [m*16, m*16+16)

  unsigned* cnt = (unsigned*)(ws) + (size_t)g*64;
  unsigned short* hbufH = (unsigned short*)(ws + WS_HBUFH);
  unsigned short* hbufL = (unsigned short*)(ws + WS_HBUFL);
  float* hfin = (float*)(ws + WS_HFIN);

  if (tid == 0) bail = 0;

  // ---- preload this group's indices
  for (int k = tid; k < SEQLEN*GB; k += 256){
    int t = k >> 4, b = k & 15;
    idxs[k] = input[t*BATCH + g*GB + b];
  }

  // ---- load split-f16 weight fragments into VGPRs (persistent; scaled x64)
  // wave wv handles gate wv; lane holds col = wv*512 + m*16 + (lane&15)
  const int ncol = wv*512 + m*16 + (lane & 15);
  const int hi = lane >> 4;
  f16x8 wxh[16], wxl[16], whh[16], whl[16];
  #pragma unroll
  for (int c = 0; c < 16; ++c){
    f16x8 xh, xl, hh, hl;
    #pragma unroll
    for (int j = 0; j < 8; ++j){
      int k = c*32 + hi*8 + j;
      float wx_ = W_ih[(size_t)k*G4H + ncol] * WSCALE;
      float wh_ = W_hh[(size_t)k*G4H + ncol] * WSCALE;
      _Float16 a = (_Float16)wx_;
      xh[j] = a; xl[j] = (_Float16)(wx_ - (float)a);
      _Float16 b = (_Float16)wh_;
      hh[j] = b; hl[j] = (_Float16)(wh_ - (float)b);
    }
    wxh[c] = xh; wxl[c] = xl; whh[c] = hh; whl[c] = hl;
  }
  const float bias_s = b_lstm[ncol] * WSCALE;

  const int grow = tid >> 4;   // staging row (batch 0..15)
  const int gseg = tid & 15;   // 32-elem segment within row

  float creg[4] = {0.f,0.f,0.f,0.f};   // cell state, tid<64 only
  const int eb = tid >> 2;             // elementwise batch row
  const int eq = tid & 3;              // elementwise col quad

  __syncthreads();

  // ---- prologue: stage x_0 into Ax (hi-plane only)
  {
    int idx = idxs[grow];
    const float4* src = (const float4*)(emb + (size_t)idx*HDIM) + gseg*8;
    char* axb = (char*)Ax;
    int sw = (grow & 7) << 4;
    #pragma unroll
    for (int q = 0; q < 8; ++q){
      float4 v = src[q];
      uint2 p;
      p.x = (unsigned)f2h(v.x) | ((unsigned)f2h(v.y) << 16);
      p.y = (unsigned)f2h(v.z) | ((unsigned)f2h(v.w) << 16);
      *(uint2*)(axb + grow*1024 + ((gseg*64 + q*8) ^ sw)) = p;
    }
  }
  __syncthreads();

  const int row = lane & 15;
  const char* axb_r = (const char*)Ax;
  const char* ahHb_r = (const char*)AhH;
  const char* ahLb_r = (const char*)AhL;
  const int rbase = row*1024;
  const int rsw = (row & 7) << 4;

  for (int t = 0; t < SEQLEN; ++t){
    // 0. issue gather for t+1 (latency hides under x-MFMA + poll)
    float4 gr[8];
    if (t + 1 < SEQLEN){
      int idx = idxs[(t+1)*16 + grow];
      const float4* src = (const float4*)(emb + (size_t)idx*HDIM) + gseg*8;
      #pragma unroll
      for (int q = 0; q < 8; ++q) gr[q] = src[q];
    }

    // 1. x-part MFMA: 2 per fragment (xh*Wh + xh*Wl), dual accumulators
    f32x4 accA = {bias_s, bias_s, bias_s, bias_s};
    f32x4 accB = {0.f, 0.f, 0.f, 0.f};
    #pragma unroll
    for (int c = 0; c < 16; c += 2){
      f16x8 a0 = *(const f16x8*)(axb_r + rbase + ((c*64 + hi*16) ^ rsw));
      f16x8 a1 = *(const f16x8*)(axb_r + rbase + (((c+1)*64 + hi*16) ^ rsw));
      accA = __builtin_amdgcn_mfma_f32_16x16x32_f16(a0, wxh[c],   accA, 0, 0, 0);
      accA = __builtin_amdgcn_mfma_f32_16x16x32_f16(a0, wxl[c],   accA, 0, 0, 0);
      accB = __builtin_amdgcn_mfma_f32_16x16x32_f16(a1, wxh[c+1], accB, 0, 0, 0);
      accB = __builtin_amdgcn_mfma_f32_16x16x32_f16(a1, wxl[c+1], accB, 0, 0, 0);
    }

    // 2-3. wait for h_{t-1} (timeout-guarded); stage hi/lo planes into LDS
    if (t > 0){
      if (tid == 0){
        unsigned target = 32u * (unsigned)t;
        int spins = 0;
        while (__hip_atomic_load(cnt, __ATOMIC_ACQUIRE, __HIP_MEMORY_SCOPE_AGENT) < target){
          __builtin_amdgcn_s_sleep(1);
          if (++spins > (1<<22)){ bail = 1; break; }
        }
      }
      __syncthreads();   // B1
      if (bail){
        // co-residency/protocol failure: mark our hfin rows NaN (diagnostic) and exit
        if (tid < 64){
          float nanv = __builtin_bit_cast(float, 0x7FC00000u);
          float4 fv = {nanv, nanv, nanv, nanv};
          *(float4*)(hfin + (size_t)(g*16 + eb)*HDIM + m*16 + eq*4) = fv;
        }
        return;
      }
      size_t base = ((size_t)(g*2 + ((t-1)&1))*16 + grow)*512;
      const unsigned long long* hbH = (const unsigned long long*)(hbufH + base) + gseg*8;
      const unsigned long long* hbL = (const unsigned long long*)(hbufL + base) + gseg*8;
      unsigned long long hv[8], lv[8];
      #pragma unroll
      for (int q = 0; q < 8; ++q){
        hv[q] = __hip_atomic_load(hbH + q, __ATOMIC_RELAXED, __HIP_MEMORY_SCOPE_AGENT);
        lv[q] = __hip_atomic_load(hbL + q, __ATOMIC_RELAXED, __HIP_MEMORY_SCOPE_AGENT);
      }
      char* ahHb = (char*)AhH;
      char* ahLb = (char*)AhL;
      int sw = (grow & 7) << 4;
      #pragma unroll
      for (int q = 0; q < 8; ++q){
        *(unsigned long long*)(ahHb + grow*1024 + ((gseg*64 + q*8) ^ sw)) = hv[q];
        *(unsigned long long*)(ahLb + grow*1024 + ((gseg*64 + q*8) ^ sw)) = lv[q];
      }
    } else {
      __syncthreads();   // B1 (uniform barrier structure)
    }

    // 3b. write A_x(t+1) hi-plane (x-MFMA of all waves completed before B1)
    if (t + 1 < SEQLEN){
      char* axb = (char*)Ax;
      int sw = (grow & 7) << 4;
      #pragma unroll
      for (int q = 0; q < 8; ++q){
        uint2 p;
        p.x = (unsigned)f2h(gr[q].x) | ((unsigned)f2h(gr[q].y) << 16);
        p.y = (unsigned)f2h(gr[q].z) | ((unsigned)f2h(gr[q].w) << 16);
        *(uint2*)(axb + grow*1024 + ((gseg*64 + q*8) ^ sw)) = p;
      }
    }
    __syncthreads();   // B2

    // 4. h-part MFMA: 3 per fragment (hh*Wh + hl*Wh + hh*Wl)
    if (t > 0){
      #pragma unroll
      for (int c = 0; c < 16; c += 2){
        f16x8 h0h = *(const f16x8*)(ahHb_r + rbase + ((c*64 + hi*16) ^ rsw));
        f16x8 h0l = *(const f16x8*)(ahLb_r + rbase + ((c*64 + hi*16) ^ rsw));
        f16x8 h1h = *(const f16x8*)(ahHb_r + rbase + (((c+1)*64 + hi*16) ^ rsw));
        f16x8 h1l = *(const f16x8*)(ahLb_r + rbase + (((c+1)*64 + hi*16) ^ rsw));
        accA = __builtin_amdgcn_mfma_f32_16x16x32_f16(h0h, whh[c],   accA, 0, 0, 0);
        accA = __builtin_amdgcn_mfma_f32_16x16x32_f16(h0l, whh[c],   accA, 0, 0, 0);
        accA = __builtin_amdgcn_mfma_f32_16x16x32_f16(h0h, whl[c],   accA, 0, 0, 0);
        accB = __builtin_amdgcn_mfma_f32_16x16x32_f16(h1h, whh[c+1], accB, 0, 0, 0);
        accB = __builtin_amdgcn_mfma_f32_16x16x32_f16(h1l, whh[c+1], accB, 0, 0, 0);
        accB = __builtin_amdgcn_mfma_f32_16x16x32_f16(h1h, whl[c+1], accB, 0, 0, 0);
      }
    }

    // 5. gates -> LDS (C layout: col=lane&15, row=(lane>>4)*4+r), unscale
    {
      f32x4 gsum = (accA + accB) * WINV;
      int cc = lane & 15, r0 = hi*4;
      #pragma unroll
      for (int r = 0; r < 4; ++r) gbuf[wv][r0 + r][cc] = gsum[r];
    }
    __syncthreads();   // B3

    // 6. elementwise LSTM cell + h exchange (wave 0 only)
    if (tid < 64){
      float hval[4];
      #pragma unroll
      for (int j = 0; j < 4; ++j){
        int ccol = eq*4 + j;
        float gi = gbuf[0][eb][ccol];
        float gf = gbuf[1][eb][ccol];
        float gg = gbuf[2][eb][ccol];
        float go = gbuf[3][eb][ccol];
        float si = 1.f/(1.f + __expf(-gi));
        float sf = 1.f/(1.f + __expf(-gf));
        float tg = 2.f/(1.f + __expf(-2.f*gg)) - 1.f;
        float c2 = sf*creg[j] + si*tg;
        creg[j] = c2;
        float so = 1.f/(1.f + __expf(-go));
        float tc = 2.f/(1.f + __expf(-2.f*c2)) - 1.f;
        hval[j] = so * tc;
      }
      if (t < SEQLEN-1){
        unsigned short hh[4], ll[4];
        #pragma unroll
        for (int j = 0; j < 4; ++j) split_f16(hval[j], hh[j], ll[j]);
        unsigned long long pvh = (unsigned long long)((unsigned)hh[0] | ((unsigned)hh[1]<<16))
                               | ((unsigned long long)((unsigned)hh[2] | ((unsigned)hh[3]<<16)) << 32);
        unsigned long long pvl = (unsigned long long)((unsigned)ll[0] | ((unsigned)ll[1]<<16))
                               | ((unsigned long long)((unsigned)ll[2] | ((unsigned)ll[3]<<16)) << 32);
        size_t off = ((size_t)(g*2 + (t&1))*16 + eb)*512 + m*16 + eq*4;
        __hip_atomic_store((unsigned long long*)(hbufH + off), pvh,
                           __ATOMIC_RELAXED, __HIP_MEMORY_SCOPE_AGENT);
        __hip_atomic_store((unsigned long long*)(hbufL + off), pvl,
                           __ATOMIC_RELAXED, __HIP_MEMORY_SCOPE_AGENT);
      } else {
        float4 fv = {hval[0], hval[1], hval[2], hval[3]};
        *(float4*)(hfin + (size_t)(g*16 + eb)*HDIM + m*16 + eq*4) = fv;
      }
    }
    __syncthreads();   // B4 (drains wave-0 stores before the add)
    if (t < SEQLEN-1 && tid == 0){
      __hip_atomic_fetch_add(cnt, 1u, __ATOMIC_RELEASE, __HIP_MEMORY_SCOPE_AGENT);
    }
  }
}

// ---------------- final decode: relu(h @ W_dec + b_dec) @ W_fc + b_fc ----
__global__ __launch_bounds__(128)
void decode_kernel(const char* __restrict__ ws, const float* __restrict__ W_dec,
                   const float* __restrict__ b_dec, const float* __restrict__ W_fc,
                   const float* __restrict__ b_fc, float* __restrict__ out)
{
  __shared__ float hs[512];
  __shared__ float red0[128], red1[128];
  const int b = blockIdx.x, tid = threadIdx.x;
  const float* hfin = (const float*)(ws + WS_HFIN);
  ((float4*)hs)[tid] = ((const float4*)(hfin + (size_t)b*512))[tid];
  __syncthreads();
  float p0 = 0.f, p1 = 0.f;
  if (tid < 100){
    float acc = b_dec[tid];
    #pragma unroll 4
    for (int k = 0; k < 512; ++k) acc += hs[k] * W_dec[k*100 + tid];
    float d = fmaxf(acc, 0.f);
    p0 = d * W_fc[tid*2 + 0];
    p1 = d * W_fc[tid*2 + 1];
  }
  red0[tid] = p0; red1[tid] = p1;
  __syncthreads();
  for (int s = 64; s > 0; s >>= 1){
    if (tid < s){ red0[tid] += red0[tid+s]; red1[tid] += red1[tid+s]; }
    __syncthreads();
  }
  if (tid == 0){
    out[b*2 + 0] = red0[0] + b_fc[0];
    out[b*2 + 1] = red1[0] + b_fc[1];
  }
}

extern "C" void kernel_launch(void* const* d_in, const int* in_sizes, int n_in,
                              void* d_out, int out_size, void* d_ws, size_t ws_size,
                              hipStream_t stream)
{
  const int*   input  = (const int*)d_in[0];
  const float* emb    = (const float*)d_in[1];
  const float* W_ih   = (const float*)d_in[2];
  const float* W_hh   = (const float*)d_in[3];
  const float* b_lstm = (const float*)d_in[4];
  const float* W_dec  = (const float*)d_in[5];
  const float* b_dec  = (const float*)d_in[6];
  const float* W_fc   = (const float*)d_in[7];
  const float* b_fc   = (const float*)d_in[8];
  float* out = (float*)d_out;
  char*  ws  = (char*)d_ws;

  // zero the group counters (ws is re-poisoned to 0xAA before every launch)
  hipMemsetAsync(ws, 0, 4096, stream);

  // plain launch: 256 blocks x 84KB LDS -> exactly 1 block/CU on 256 CUs,
  // all co-resident (persistent-kernel pattern); spin-sync has NaN-marking timeout.
  lstm_fused<<<dim3(256), dim3(256), 0, stream>>>(input, emb, W_ih, W_hh, b_lstm, ws);

  decode_kernel<<<dim3(128), dim3(128), 0, stream>>>(ws, W_dec, b_dec, W_fc, b_fc, out);
}

// Round 5
// 5320.249 us; speedup vs baseline: 1.0357x; 1.0357x over previous
//
#include <hip/hip_runtime.h>

#define HDIM 512
#define G4H 2048
#define SEQLEN 512
#define BATCH 128
#define GB 16         // batch rows per group
#define WSCALE 64.0f
#define WINV   0.015625f

typedef __attribute__((ext_vector_type(8))) _Float16 f16x8;
typedef __attribute__((ext_vector_type(4))) float f32x4;

__device__ __forceinline__ unsigned short f2h(float x){
  return __builtin_bit_cast(unsigned short, (_Float16)x);
}
__device__ __forceinline__ void split_f16(float v, unsigned short& h, unsigned short& l){
  _Float16 a = (_Float16)v;
  _Float16 b = (_Float16)(v - (float)a);
  h = __builtin_bit_cast(unsigned short, a);
  l = __builtin_bit_cast(unsigned short, b);
}

// workspace layout
#define WS_FLAG  0                                   // [8 groups][32 members] u32, 128B apart = 32KB
#define WS_HBUFH 32768                               // [8][2][16][512] f16 = 256KB
#define WS_HBUFL (32768 + 262144)                    // lo plane, 256KB
#define WS_HFIN  (32768 + 2*262144)                  // [128][512] f32 = 256KB

__global__ __launch_bounds__(256, 1)
void lstm_fused(const int* __restrict__ input, const float* __restrict__ emb,
                const float* __restrict__ W_ih, const float* __restrict__ W_hh,
                const float* __restrict__ b_lstm, char* __restrict__ ws)
{
  __shared__ __align__(16) unsigned short Ax[2][16*512]; // x hi-plane, double-buffered, 32KB
  __shared__ __align__(16) unsigned short AhH[16*512];   // h hi-plane, 16KB
  __shared__ __align__(16) unsigned short AhL[16*512];   // h lo-plane, 16KB
  __shared__ float gbuf[4][16][17];                      // gate exchange (+1 pad), ~4.3KB
  __shared__ int idxs[SEQLEN*GB];                        // 32KB  -> ~101KB total, 1 block/CU
  __shared__ int bail;

  const int tid  = threadIdx.x;
  const int lane = tid & 63;
  const int wv   = tid >> 6;          // wave index == gate index (i,f,g,o)
  const int bid  = blockIdx.x;
  const int g    = bid & 7;           // group (co-located on one XCD via bid%8 round-robin)
  const int m    = bid >> 3;          // member 0..31: owns h-cols [m*16, m*16+16)

  unsigned short* hbufH = (unsigned short*)(ws + WS_HBUFH);
  unsigned short* hbufL = (unsigned short*)(ws + WS_HBUFL);
  float* hfin = (float*)(ws + WS_HFIN);
  unsigned* myflag = (unsigned*)(ws + WS_FLAG + (size_t)(g*32 + m)*128);

  if (tid == 0) bail = 0;

  // ---- preload this group's indices (coalesced)
  for (int k = tid; k < SEQLEN*GB; k += 256){
    int t = k >> 4, b = k & 15;
    idxs[k] = input[t*BATCH + g*GB + b];
  }

  // ---- load split-f16 weight fragments into VGPRs (persistent; scaled x64)
  const int ncol = wv*512 + m*16 + (lane & 15);
  const int hi = lane >> 4;
  f16x8 wxh[16], wxl[16], whh[16], whl[16];
  #pragma unroll
  for (int c = 0; c < 16; ++c){
    f16x8 xh, xl, hh, hl;
    #pragma unroll
    for (int j = 0; j < 8; ++j){
      int k = c*32 + hi*8 + j;
      float wx_ = W_ih[(size_t)k*G4H + ncol] * WSCALE;
      float wh_ = W_hh[(size_t)k*G4H + ncol] * WSCALE;
      _Float16 a = (_Float16)wx_;
      xh[j] = a; xl[j] = (_Float16)(wx_ - (float)a);
      _Float16 b = (_Float16)wh_;
      hh[j] = b; hl[j] = (_Float16)(wh_ - (float)b);
    }
    wxh[c] = xh; wxl[c] = xl; whh[c] = hh; whl[c] = hl;
  }
  const float bias_s = b_lstm[ncol] * WSCALE;

  // staging mapping: grow = tid&15 (16 consecutive lanes -> 16 distinct rows)
  // -> XOR swizzle spreads them across 8 bank-groups: 2-way (free) vs old 8-way
  const int grow = tid & 15;   // staging row (batch 0..15)
  const int gseg = tid >> 4;   // 32-elem segment within row
  const int sw   = (grow & 7) << 4;

  float creg[4] = {0.f,0.f,0.f,0.f};   // cell state, tid<64 only
  const int eb = tid >> 2;             // elementwise batch row
  const int eq = tid & 3;              // elementwise col quad

  __syncthreads();

  // ---- prologue: stage x_0 into Ax[0] (hi-plane only)
  {
    int idx = idxs[grow];
    const float4* src = (const float4*)(emb + (size_t)idx*HDIM) + gseg*8;
    char* axb = (char*)Ax[0];
    #pragma unroll
    for (int q = 0; q < 8; ++q){
      float4 v = src[q];
      uint2 p;
      p.x = (unsigned)f2h(v.x) | ((unsigned)f2h(v.y) << 16);
      p.y = (unsigned)f2h(v.z) | ((unsigned)f2h(v.w) << 16);
      *(uint2*)(axb + grow*1024 + ((gseg*64 + q*8) ^ sw)) = p;
    }
  }
  __syncthreads();

  const int row = lane & 15;
  const char* ahHb_r = (const char*)AhH;
  const char* ahLb_r = (const char*)AhL;
  const int rbase = row*1024;
  const int rsw = (row & 7) << 4;

  for (int t = 0; t < SEQLEN; ++t){
    // (a) issue gather for t+1 (latency hides under poll + x-MFMA)
    float4 gr[8];
    if (t + 1 < SEQLEN){
      int idx = idxs[(t+1)*16 + grow];
      const float4* src = (const float4*)(emb + (size_t)idx*HDIM) + gseg*8;
      #pragma unroll
      for (int q = 0; q < 8; ++q) gr[q] = src[q];
    }

    // (b) poll per-member flags — wave 1 lanes 0..31, in parallel (overlaps
    //     wave 0's cell epilogue of step t-1; no RMW serialization)
    if (t > 0 && tid >= 64 && tid < 96){
      const unsigned* fp = (const unsigned*)(ws + WS_FLAG + (size_t)(g*32 + (tid-64))*128);
      int spins = 0;
      while (__hip_atomic_load(fp, __ATOMIC_ACQUIRE, __HIP_MEMORY_SCOPE_AGENT) < (unsigned)t){
        __builtin_amdgcn_s_sleep(1);
        if (++spins > (1<<22)){ bail = 1; break; }
      }
    }
    __syncthreads();   // B1
    if (bail){
      if (tid < 64){
        float nanv = __builtin_bit_cast(float, 0x7FC00000u);
        float4 fv = {nanv, nanv, nanv, nanv};
        *(float4*)(hfin + (size_t)(g*16 + eb)*HDIM + m*16 + eq*4) = fv;
      }
      return;
    }

    // (c) issue h_{t-1} loads (L2-resident on this XCD); latency hidden by (d)
    unsigned long long hv[8], lv[8];
    if (t > 0){
      size_t base = ((size_t)(g*2 + ((t-1)&1))*16 + grow)*512;
      const unsigned long long* hbH = (const unsigned long long*)(hbufH + base) + gseg*8;
      const unsigned long long* hbL = (const unsigned long long*)(hbufL + base) + gseg*8;
      #pragma unroll
      for (int q = 0; q < 8; ++q){
        hv[q] = __hip_atomic_load(hbH + q, __ATOMIC_RELAXED, __HIP_MEMORY_SCOPE_AGENT);
        lv[q] = __hip_atomic_load(hbL + q, __ATOMIC_RELAXED, __HIP_MEMORY_SCOPE_AGENT);
      }
    }

    // (d) x-part MFMA on Ax[t&1]: 2 per fragment (xh*Wh + xh*Wl)
    f32x4 accA = {bias_s, bias_s, bias_s, bias_s};
    f32x4 accB = {0.f, 0.f, 0.f, 0.f};
    {
      const char* axb_r = (const char*)Ax[t & 1];
      #pragma unroll
      for (int c = 0; c < 16; c += 2){
        f16x8 a0 = *(const f16x8*)(axb_r + rbase + ((c*64 + hi*16) ^ rsw));
        f16x8 a1 = *(const f16x8*)(axb_r + rbase + (((c+1)*64 + hi*16) ^ rsw));
        accA = __builtin_amdgcn_mfma_f32_16x16x32_f16(a0, wxh[c],   accA, 0, 0, 0);
        accA = __builtin_amdgcn_mfma_f32_16x16x32_f16(a0, wxl[c],   accA, 0, 0, 0);
        accB = __builtin_amdgcn_mfma_f32_16x16x32_f16(a1, wxh[c+1], accB, 0, 0, 0);
        accB = __builtin_amdgcn_mfma_f32_16x16x32_f16(a1, wxl[c+1], accB, 0, 0, 0);
      }
    }

    // (e) stage Ah hi/lo (h loads have landed) + Ax[(t+1)&1] (gather landed)
    if (t > 0){
      char* ahHb = (char*)AhH;
      char* ahLb = (char*)AhL;
      #pragma unroll
      for (int q = 0; q < 8; ++q){
        *(unsigned long long*)(ahHb + grow*1024 + ((gseg*64 + q*8) ^ sw)) = hv[q];
        *(unsigned long long*)(ahLb + grow*1024 + ((gseg*64 + q*8) ^ sw)) = lv[q];
      }
    }
    if (t + 1 < SEQLEN){
      char* axb = (char*)Ax[(t+1) & 1];
      #pragma unroll
      for (int q = 0; q < 8; ++q){
        uint2 p;
        p.x = (unsigned)f2h(gr[q].x) | ((unsigned)f2h(gr[q].y) << 16);
        p.y = (unsigned)f2h(gr[q].z) | ((unsigned)f2h(gr[q].w) << 16);
        *(uint2*)(axb + grow*1024 + ((gseg*64 + q*8) ^ sw)) = p;
      }
    }
    __syncthreads();   // B2

    // (f) h-part MFMA: 3 per fragment (hh*Wh + hl*Wh + hh*Wl)
    if (t > 0){
      #pragma unroll
      for (int c = 0; c < 16; c += 2){
        f16x8 h0h = *(const f16x8*)(ahHb_r + rbase + ((c*64 + hi*16) ^ rsw));
        f16x8 h0l = *(const f16x8*)(ahLb_r + rbase + ((c*64 + hi*16) ^ rsw));
        f16x8 h1h = *(const f16x8*)(ahHb_r + rbase + (((c+1)*64 + hi*16) ^ rsw));
        f16x8 h1l = *(const f16x8*)(ahLb_r + rbase + (((c+1)*64 + hi*16) ^ rsw));
        accA = __builtin_amdgcn_mfma_f32_16x16x32_f16(h0h, whh[c],   accA, 0, 0, 0);
        accA = __builtin_amdgcn_mfma_f32_16x16x32_f16(h0l, whh[c],   accA, 0, 0, 0);
        accA = __builtin_amdgcn_mfma_f32_16x16x32_f16(h0h, whl[c],   accA, 0, 0, 0);
        accB = __builtin_amdgcn_mfma_f32_16x16x32_f16(h1h, whh[c+1], accB, 0, 0, 0);
        accB = __builtin_amdgcn_mfma_f32_16x16x32_f16(h1l, whh[c+1], accB, 0, 0, 0);
        accB = __builtin_amdgcn_mfma_f32_16x16x32_f16(h1h, whl[c+1], accB, 0, 0, 0);
      }
    }

    // (g) gates -> LDS (C layout: col=lane&15, row=(lane>>4)*4+r), unscale
    {
      f32x4 gsum = (accA + accB) * WINV;
      int cc = lane & 15, r0 = hi*4;
      #pragma unroll
      for (int r = 0; r < 4; ++r) gbuf[wv][r0 + r][cc] = gsum[r];
    }
    __syncthreads();   // B3

    // (h) elementwise LSTM cell + h exchange (wave 0 only); flag via release
    //     store by tid0 (wave-wide vmcnt drain orders wave 0's h stores first)
    if (tid < 64){
      float hval[4];
      #pragma unroll
      for (int j = 0; j < 4; ++j){
        int ccol = eq*4 + j;
        float gi = gbuf[0][eb][ccol];
        float gf = gbuf[1][eb][ccol];
        float gg = gbuf[2][eb][ccol];
        float go = gbuf[3][eb][ccol];
        float si = 1.f/(1.f + __expf(-gi));
        float sf = 1.f/(1.f + __expf(-gf));
        float tg = 2.f/(1.f + __expf(-2.f*gg)) - 1.f;
        float c2 = sf*creg[j] + si*tg;
        creg[j] = c2;
        float so = 1.f/(1.f + __expf(-go));
        float tc = 2.f/(1.f + __expf(-2.f*c2)) - 1.f;
        hval[j] = so * tc;
      }
      if (t < SEQLEN-1){
        unsigned short hh[4], ll[4];
        #pragma unroll
        for (int j = 0; j < 4; ++j) split_f16(hval[j], hh[j], ll[j]);
        unsigned long long pvh = (unsigned long long)((unsigned)hh[0] | ((unsigned)hh[1]<<16))
                               | ((unsigned long long)((unsigned)hh[2] | ((unsigned)hh[3]<<16)) << 32);
        unsigned long long pvl = (unsigned long long)((unsigned)ll[0] | ((unsigned)ll[1]<<16))
                               | ((unsigned long long)((unsigned)ll[2] | ((unsigned)ll[3]<<16)) << 32);
        size_t off = ((size_t)(g*2 + (t&1))*16 + eb)*512 + m*16 + eq*4;
        __hip_atomic_store((unsigned long long*)(hbufH + off), pvh,
                           __ATOMIC_RELAXED, __HIP_MEMORY_SCOPE_AGENT);
        __hip_atomic_store((unsigned long long*)(hbufL + off), pvl,
                           __ATOMIC_RELAXED, __HIP_MEMORY_SCOPE_AGENT);
        if (tid == 0){
          __hip_atomic_store(myflag, (unsigned)(t+1),
                             __ATOMIC_RELEASE, __HIP_MEMORY_SCOPE_AGENT);
        }
      } else {
        float4 fv = {hval[0], hval[1], hval[2], hval[3]};
        *(float4*)(hfin + (size_t)(g*16 + eb)*HDIM + m*16 + eq*4) = fv;
      }
    }
    // no B4: gbuf WAR is covered by B1/B2 of step t+1; flag ordering by release
  }
}

// ---------------- final decode: relu(h @ W_dec + b_dec) @ W_fc + b_fc ----
__global__ __launch_bounds__(128)
void decode_kernel(const char* __restrict__ ws, const float* __restrict__ W_dec,
                   const float* __restrict__ b_dec, const float* __restrict__ W_fc,
                   const float* __restrict__ b_fc, float* __restrict__ out)
{
  __shared__ float hs[512];
  __shared__ float red0[128], red1[128];
  const int b = blockIdx.x, tid = threadIdx.x;
  const float* hfin = (const float*)(ws + WS_HFIN);
  ((float4*)hs)[tid] = ((const float4*)(hfin + (size_t)b*512))[tid];
  __syncthreads();
  float p0 = 0.f, p1 = 0.f;
  if (tid < 100){
    float acc = b_dec[tid];
    #pragma unroll 4
    for (int k = 0; k < 512; ++k) acc += hs[k] * W_dec[k*100 + tid];
    float d = fmaxf(acc, 0.f);
    p0 = d * W_fc[tid*2 + 0];
    p1 = d * W_fc[tid*2 + 1];
  }
  red0[tid] = p0; red1[tid] = p1;
  __syncthreads();
  for (int s = 64; s > 0; s >>= 1){
    if (tid < s){ red0[tid] += red0[tid+s]; red1[tid] += red1[tid+s]; }
    __syncthreads();
  }
  if (tid == 0){
    out[b*2 + 0] = red0[0] + b_fc[0];
    out[b*2 + 1] = red1[0] + b_fc[1];
  }
}

extern "C" void kernel_launch(void* const* d_in, const int* in_sizes, int n_in,
                              void* d_out, int out_size, void* d_ws, size_t ws_size,
                              hipStream_t stream)
{
  const int*   input  = (const int*)d_in[0];
  const float* emb    = (const float*)d_in[1];
  const float* W_ih   = (const float*)d_in[2];
  const float* W_hh   = (const float*)d_in[3];
  const float* b_lstm = (const float*)d_in[4];
  const float* W_dec  = (const float*)d_in[5];
  const float* b_dec  = (const float*)d_in[6];
  const float* W_fc   = (const float*)d_in[7];
  const float* b_fc   = (const float*)d_in[8];
  float* out = (float*)d_out;
  char*  ws  = (char*)d_ws;

  // zero the flag region (ws is re-poisoned to 0xAA before every launch)
  hipMemsetAsync(ws, 0, 32768, stream);

  // plain launch: 256 blocks x ~101KB LDS -> exactly 1 block/CU on 256 CUs,
  // all co-resident (persistent-kernel pattern); spin-sync has NaN-marking timeout.
  lstm_fused<<<dim3(256), dim3(256), 0, stream>>>(input, emb, W_ih, W_hh, b_lstm, ws);

  decode_kernel<<<dim3(128), dim3(128), 0, stream>>>(ws, W_dec, b_dec, W_fc, b_fc, out);
}